// Round 6
// baseline (80.750 us; speedup 1.0000x reference)
//
#include <hip/hip_runtime.h>

typedef _Float16 h8  __attribute__((ext_vector_type(8)));
typedef float    f32x16 __attribute__((ext_vector_type(16)));

#define BB      16
#define NPTS    4096
#define WAVES   4                       // waves per block
#define RPB     (WAVES * 32)            // 128 rows per block
#define CHUNK   512                     // cols staged per LDS chunk
#define NCHUNK  (NPTS / CHUNK)          // 8
#define TPB     (WAVES * 64)            // 256

// d2(a,b) = s1 + s2 - 2 a.b  via K=13 fp16-split dot:
//  A = [ah,ah,al, s1h,s1l, 1,1, 0..]   B = [-2bh,-2bl,-2bh, 1,1, s2h,s2l, 0..]
// per-k pairing (k0..12):
//  k0..2 : ah * -2bh   k3..5: ah * -2bl   k6..8: al * -2bh
//  k9,k10: s1h,s1l * 1       k11,k12: 1 * s2h,s2l
__global__ __launch_bounds__(TPB) void chamfer_mfma(
    const float* __restrict__ xyz1,
    const float* __restrict__ xyz2,
    float* __restrict__ out)
{
    // col c stored at byte c*32 (+16 for k-half 1): a 32-col tile is a
    // contiguous 1024B region -> wave ds_read_b128 is conflict-free.
    __shared__ __align__(16) _Float16 sb[2][CHUNK * 16];

    const int tid  = threadIdx.x;
    const int lane = tid & 63;
    const int wv   = tid >> 6;
    const int rb   = blockIdx.x;       // row-block 0..31
    const int b    = blockIdx.y;       // batch
    const int dir  = blockIdx.z;       // 0: rows=set1, 1: rows=set2

    const float* qbase = (dir == 0 ? xyz1 : xyz2) + b * NPTS * 3;
    const float* dbase = (dir == 0 ? xyz2 : xyz1) + b * NPTS * 3;

    // ---- A fragment: row = lane&31, k-half = lane>>5 ----
    const int row = rb * RPB + wv * 32 + (lane & 31);
    h8 afrag;
    {
        float x = qbase[row * 3 + 0], y = qbase[row * 3 + 1], z = qbase[row * 3 + 2];
        float s = fmaf(x, x, fmaf(y, y, z * z));
        _Float16 xh = (_Float16)x, yh = (_Float16)y, zh = (_Float16)z;
        _Float16 xl = (_Float16)(x - (float)xh);
        _Float16 yl = (_Float16)(y - (float)yh);
        _Float16 zl = (_Float16)(z - (float)zh);
        _Float16 sh = (_Float16)s;
        _Float16 sl = (_Float16)(s - (float)sh);
        _Float16 one = (_Float16)1.0f, zero = (_Float16)0.0f;
        if (lane < 32) afrag = h8{xh, yh, zh, xh, yh, zh, xl, yl};
        else           afrag = h8{zl, sh, sl, one, one, zero, zero, zero};
    }

    const f32x16 Z = {};               // zero C operand, lives in regs
    float rm[16];
#pragma unroll
    for (int r = 0; r < 16; ++r) rm[r] = 3.0e38f;

    const int laneoff = (lane & 31) * 16 + (lane >> 5) * 8;   // in halfs

    float v[4][3];                     // prefetch regs: 4 (col,half) items

    // T14-split staging: issue loads early, convert+write late.
    auto stage_load = [&](int ch) {
        const float* p = dbase + ch * CHUNK * 3;
#pragma unroll
        for (int t = 0; t < 4; ++t) {
            int c = (tid + t * TPB) >> 1;
            v[t][0] = p[c * 3 + 0];
            v[t][1] = p[c * 3 + 1];
            v[t][2] = p[c * 3 + 2];
        }
    };
    auto stage_write = [&](int buf) {
#pragma unroll
        for (int t = 0; t < 4; ++t) {
            int it = tid + t * TPB;
            int c = it >> 1, hf = it & 1;
            float x = v[t][0], y = v[t][1], z = v[t][2];
            float s = fmaf(x, x, fmaf(y, y, z * z));
            _Float16 xh = (_Float16)x, yh = (_Float16)y, zh = (_Float16)z;
            _Float16 m2xh = (_Float16)(-2.0f) * xh;   // exact
            _Float16 m2yh = (_Float16)(-2.0f) * yh;
            _Float16 m2zh = (_Float16)(-2.0f) * zh;
            _Float16 m2xl = (_Float16)(-2.0f * (x - (float)xh));
            _Float16 m2yl = (_Float16)(-2.0f * (y - (float)yh));
            _Float16 m2zl = (_Float16)(-2.0f * (z - (float)zh));
            _Float16 sh = (_Float16)s;
            _Float16 sl = (_Float16)(s - (float)sh);
            _Float16 one = (_Float16)1.0f, zero = (_Float16)0.0f;
            h8 w;
            if (hf == 0) w = h8{m2xh, m2yh, m2zh, m2xl, m2yl, m2zl, m2xh, m2yh};
            else         w = h8{m2zh, one, one, sh, sl, zero, zero, zero};
            *(h8*)&sb[buf][c * 16 + hf * 8] = w;
        }
    };

    auto sweep = [&](int buf) {
        const _Float16* base = &sb[buf][0];
#pragma unroll
        for (int t = 0; t < CHUNK / 32; t += 2) {
            h8 b0 = *(const h8*)(base + t * 512 + laneoff);
            h8 b1 = *(const h8*)(base + (t + 1) * 512 + laneoff);
            f32x16 a0 = __builtin_amdgcn_mfma_f32_32x32x16_f16(afrag, b0, Z, 0, 0, 0);
            f32x16 a1 = __builtin_amdgcn_mfma_f32_32x32x16_f16(afrag, b1, Z, 0, 0, 0);
#pragma unroll
            for (int r = 0; r < 16; ++r)
                rm[r] = fminf(fminf(a0[r], a1[r]), rm[r]);   // v_min3_f32
        }
    };

    stage_load(0);
    stage_write(0);
    __syncthreads();
    for (int ch = 0; ch < NCHUNK; ++ch) {
        int buf = ch & 1;
        if (ch + 1 < NCHUNK) stage_load(ch + 1);
        sweep(buf);
        if (ch + 1 < NCHUNK) stage_write(buf ^ 1);
        __syncthreads();
    }

    // ---- reduce rm across the 32 col-lanes (butterfly), then store ----
#pragma unroll
    for (int r = 0; r < 16; ++r) {
        float m = rm[r];
        m = fminf(m, __shfl_xor(m, 1));
        m = fminf(m, __shfl_xor(m, 2));
        m = fminf(m, __shfl_xor(m, 4));
        m = fminf(m, __shfl_xor(m, 8));
        m = fminf(m, __shfl_xor(m, 16));
        rm[r] = m;
    }
    if ((lane & 31) == 0) {
        const int half = lane >> 5;
        float* o = out + dir * (BB * NPTS) + b * NPTS + rb * RPB + wv * 32;
#pragma unroll
        for (int r = 0; r < 16; ++r) {
            int rr = (r & 3) + 8 * (r >> 2) + 4 * half;   // C/D row mapping (m74/m101)
            o[rr] = fmaxf(rm[r], 0.0f);
        }
    }
}

extern "C" void kernel_launch(void* const* d_in, const int* in_sizes, int n_in,
                              void* d_out, int out_size, void* d_ws, size_t ws_size,
                              hipStream_t stream) {
    const float* xyz1 = (const float*)d_in[0];
    const float* xyz2 = (const float*)d_in[1];
    float* out = (float*)d_out;

    dim3 grid(NPTS / RPB, BB, 2);      // 32 x 16 x 2 = 1024 blocks
    hipLaunchKernelGGL(chamfer_mfma, grid, dim3(TPB), 0, stream, xyz1, xyz2, out);
}

// Round 7
// 37.353 us; speedup vs baseline: 2.1618x; 2.1618x over previous
//
#include <hip/hip_runtime.h>

typedef _Float16 h8     __attribute__((ext_vector_type(8)));
typedef float    f32x16 __attribute__((ext_vector_type(16)));

#define BB      16
#define NPTS    4096
#define WAVES   4                       // waves per block
#define RPW     64                      // rows per wave = 2 row-blocks of 32
#define RPB     (WAVES * RPW)           // 256 rows per block
#define CHUNK   512                     // cols staged per LDS chunk
#define NCHUNK  (NPTS / CHUNK)          // 8
#define TPB     (WAVES * 64)            // 256

// d2(a,b) = s1 + s2 - 2 a.b via K=13 fp16-split dot (proven in R6, absmax 1e-3):
//  A half0 = [xh,yh,zh, xh,yh,zh, xl,yl]   A half1 = [zl, s1h,s1l, 1,1, 0,0,0]
//  B half0 = [-2xh,-2yh,-2zh, -2xl,-2yl,-2zl, -2xh,-2yh]
//  B half1 = [-2zh, 1,1, s2h,s2l, 0,0,0]
// LDS layout (conflict-free): tile t (32 cols), k-half hf, col c:
//   half-offset = t*512 + hf*256 + (c&31)*8  -> wave read is linear 1024B.
__global__ __launch_bounds__(TPB) void chamfer_mfma(
    const float* __restrict__ xyz1,
    const float* __restrict__ xyz2,
    float* __restrict__ out)
{
    __shared__ __align__(16) _Float16 sb[2][CHUNK * 16];

    const int tid  = threadIdx.x;
    const int lane = tid & 63;
    const int wv   = tid >> 6;
    const int rb   = blockIdx.x;       // row-block 0..15
    const int b    = blockIdx.y;       // batch
    const int dir  = blockIdx.z;       // 0: rows=set1, 1: rows=set2

    const float* qbase = (dir == 0 ? xyz1 : xyz2) + b * NPTS * 3;
    const float* dbase = (dir == 0 ? xyz2 : xyz1) + b * NPTS * 3;

    // ---- two A fragments per wave (row-blocks of 32) ----
    h8 af[2];
#pragma unroll
    for (int rbi = 0; rbi < 2; ++rbi) {
        const int row = rb * RPB + wv * RPW + rbi * 32 + (lane & 31);
        float x = qbase[row * 3 + 0], y = qbase[row * 3 + 1], z = qbase[row * 3 + 2];
        float s = fmaf(x, x, fmaf(y, y, z * z));
        _Float16 xh = (_Float16)x, yh = (_Float16)y, zh = (_Float16)z;
        _Float16 xl = (_Float16)(x - (float)xh);
        _Float16 yl = (_Float16)(y - (float)yh);
        _Float16 zl = (_Float16)(z - (float)zh);
        _Float16 sh = (_Float16)s;
        _Float16 sl = (_Float16)(s - (float)sh);
        _Float16 one = (_Float16)1.0f, zero = (_Float16)0.0f;
        af[rbi] = (lane < 32) ? h8{xh, yh, zh, xh, yh, zh, xl, yl}
                              : h8{zl, sh, sl, one, one, zero, zero, zero};
    }

    const f32x16 Z = {};
    float rm[2][16];
#pragma unroll
    for (int rbi = 0; rbi < 2; ++rbi)
#pragma unroll
        for (int r = 0; r < 16; ++r) rm[rbi][r] = 3.0e38f;

    const int loff = ((lane >> 5) << 8) + (lane & 31) * 8;   // halfs

    float v[4][3];

    auto stage_load = [&](int ch) {
        const float* p = dbase + ch * CHUNK * 3;
#pragma unroll
        for (int t = 0; t < 4; ++t) {
            int c = (tid + t * TPB) >> 1;
            v[t][0] = p[c * 3 + 0];
            v[t][1] = p[c * 3 + 1];
            v[t][2] = p[c * 3 + 2];
        }
    };
    auto stage_write = [&](int buf) {
#pragma unroll
        for (int t = 0; t < 4; ++t) {
            int it = tid + t * TPB;
            int c = it >> 1, hf = it & 1;
            float x = v[t][0], y = v[t][1], z = v[t][2];
            float s = fmaf(x, x, fmaf(y, y, z * z));
            _Float16 xh = (_Float16)x, yh = (_Float16)y, zh = (_Float16)z;
            _Float16 m2xh = (_Float16)(-2.0f) * xh;
            _Float16 m2yh = (_Float16)(-2.0f) * yh;
            _Float16 m2zh = (_Float16)(-2.0f) * zh;
            _Float16 m2xl = (_Float16)(-2.0f * (x - (float)xh));
            _Float16 m2yl = (_Float16)(-2.0f * (y - (float)yh));
            _Float16 m2zl = (_Float16)(-2.0f * (z - (float)zh));
            _Float16 sh = (_Float16)s;
            _Float16 sl = (_Float16)(s - (float)sh);
            _Float16 one = (_Float16)1.0f, zero = (_Float16)0.0f;
            h8 w = (hf == 0) ? h8{m2xh, m2yh, m2zh, m2xl, m2yl, m2zl, m2xh, m2yh}
                             : h8{m2zh, one, one, sh, sl, zero, zero, zero};
            int off = (c >> 5) * 512 + (hf << 8) + (c & 31) * 8;
            *(h8*)&sb[buf][off] = w;
        }
    };

    auto sweep = [&](int buf) {
        const _Float16* base = &sb[buf][0];
#pragma unroll 2
        for (int t = 0; t < CHUNK / 32; t += 2) {
            h8 b0 = *(const h8*)(base + t * 512 + loff);
            h8 b1 = *(const h8*)(base + (t + 1) * 512 + loff);
#pragma unroll
            for (int rbi = 0; rbi < 2; ++rbi) {
                f32x16 a0 = __builtin_amdgcn_mfma_f32_32x32x16_f16(af[rbi], b0, Z, 0, 0, 0);
                f32x16 a1 = __builtin_amdgcn_mfma_f32_32x32x16_f16(af[rbi], b1, Z, 0, 0, 0);
#pragma unroll
                for (int r = 0; r < 16; ++r)
                    rm[rbi][r] = fminf(fminf(a0[r], a1[r]), rm[rbi][r]);  // v_min3_f32
            }
        }
    };

    stage_load(0);
    stage_write(0);
    __syncthreads();
#pragma unroll 1
    for (int ch = 0; ch < NCHUNK; ++ch) {
        int buf = ch & 1;
        if (ch + 1 < NCHUNK) stage_load(ch + 1);
        sweep(buf);
        if (ch + 1 < NCHUNK) stage_write(buf ^ 1);
        __syncthreads();
    }

    // ---- reduce over the 32 col-lanes (butterfly within each half), store ----
#pragma unroll
    for (int rbi = 0; rbi < 2; ++rbi)
#pragma unroll
        for (int r = 0; r < 16; ++r) {
            float m = rm[rbi][r];
            m = fminf(m, __shfl_xor(m, 1));
            m = fminf(m, __shfl_xor(m, 2));
            m = fminf(m, __shfl_xor(m, 4));
            m = fminf(m, __shfl_xor(m, 8));
            m = fminf(m, __shfl_xor(m, 16));
            rm[rbi][r] = m;
        }
    if ((lane & 31) == 0) {
        const int half = lane >> 5;
        float* o = out + dir * (BB * NPTS) + b * NPTS + rb * RPB + wv * RPW;
#pragma unroll
        for (int rbi = 0; rbi < 2; ++rbi)
#pragma unroll
            for (int r = 0; r < 16; ++r) {
                int rr = (r & 3) + 8 * (r >> 2) + 4 * half;   // C/D row map (m74/m101)
                o[rbi * 32 + rr] = fmaxf(rm[rbi][r], 0.0f);
            }
    }
}

extern "C" void kernel_launch(void* const* d_in, const int* in_sizes, int n_in,
                              void* d_out, int out_size, void* d_ws, size_t ws_size,
                              hipStream_t stream) {
    const float* xyz1 = (const float*)d_in[0];
    const float* xyz2 = (const float*)d_in[1];
    float* out = (float*)d_out;

    dim3 grid(NPTS / RPB, BB, 2);      // 16 x 16 x 2 = 512 blocks
    hipLaunchKernelGGL(chamfer_mfma, grid, dim3(TPB), 0, stream, xyz1, xyz2, out);
}